// Round 4
// baseline (450.932 us; speedup 1.0000x reference)
//
#include <hip/hip_runtime.h>
#include <hip/hip_bf16.h>
#include <stdint.h>

// ---------------------------------------------------------------------------
// Round 7b: RT=2 B-reuse at 16 waves/CU. 64-row tile, 256 thr, 4 waves.
//  - All N=256 layers split into two sequential 128-col passes (CT=1) so the
//    accumulator is always 32 regs; 256-wide intermediates never materialize:
//    L1 half -> P buffer -> partial-K of L2 (acc-chained) -> overwrite.
//  - Single 17 KB stream buffer. LDS 35 KB -> 4 blocks/CU; reg peak ~105
//    under the 128 cap of __launch_bounds__(256,4) -> no spill (r6 lesson:
//    VGPR pool = 512/SIMD; (512,6) cap 85 caused 94 MB scratch writes).
//  - Weight L2 traffic halves vs r5: 0.5 KB B-fetch per MFMA.
//  (7b: fixed missing [rt] index in final32 accumulator access.)
// ---------------------------------------------------------------------------

typedef __attribute__((ext_vector_type(8))) short short8_t;
typedef __attribute__((ext_vector_type(16))) float f32x16;

#define ROWS 64
#define NWG  2048            // 131072 / 64 exactly (4 WGs per batch)
#define NTHR 256

// LDS layout (bytes)
#define OFF_P     0          // [64][136] shorts = 17408 B (stream buf / B2a half)
#define OFF_A     17408      // [64][136] shorts
#define OFF_MASK  34816      // 64 floats
#define LDS_TOTAL 35072

__device__ __forceinline__ short f2bf(float f) {
  union { float f; uint32_t u; } v; v.f = f;
  uint32_t r = (v.u + 0x7FFFu + ((v.u >> 16) & 1u)) >> 16;  // RNE
  return (short)r;
}
__device__ __forceinline__ float bf2f(short b) {
  union { uint32_t u; float f; } v; v.u = ((uint32_t)(uint16_t)b) << 16;
  return v.f;
}

// ---- MFMA block: RT=2 rows, CT=1 col-block. A from LDS, B coalesced from
// fragment-ordered global.
// Weight layout: elem off = ((cb*KT16 + ks)<<9) + lane*8 + j
//   maps to logical n = cb*32 + (lane&31), k = ks*16 + (lane>>5)*8 + j.
// A: lane n32 -> act rows {n32, 32+n32}, k = ks*16 + q32*8 + j (local). ks0
// offsets only B, so partial-K passes read A with local k. Dual k-mapping
// matches B's, so any k-permutation cancels in the dot product.
template <int KT16, int KSTEPS>
__device__ __forceinline__ void gemm32(const short* actin, int Sin,
                                       const short* __restrict__ wsB, int ks0, int cb,
                                       f32x16 (&acc)[2], int lane) {
  const int n32 = lane & 31, q32 = lane >> 5;
#pragma unroll
  for (int ks = 0; ks < KSTEPS; ++ks) {
    const int kl = ks * 16 + q32 * 8;
    const short8_t b = *(const short8_t*)(wsB + ((cb * KT16 + ks0 + ks) << 9) + lane * 8);
    short8_t a[2];
#pragma unroll
    for (int rt = 0; rt < 2; ++rt)
      a[rt] = *(const short8_t*)(actin + (rt * 32 + n32) * Sin + kl);
#pragma unroll
    for (int rt = 0; rt < 2; ++rt)
      acc[rt] = __builtin_amdgcn_mfma_f32_32x32x16_bf16(a[rt], b, acc[rt], 0, 0, 0);
  }
}

// C/D layout (verified m74/m101): col = lane&31, row = (reg&3)+8*(reg>>2)+4*(lane>>5)
// bias may be pre-offset (split layers pass bias+h*128 with local c0).
template <int ACTF>
__device__ __forceinline__ void epi32(f32x16 (&acc)[2], short* actout, int Sout,
                                      const float* __restrict__ bias, int c0,
                                      int n32, int q32) {
  const int c = c0 + n32;
  const float bv = bias[c];
#pragma unroll
  for (int rt = 0; rt < 2; ++rt)
#pragma unroll
    for (int reg = 0; reg < 16; ++reg) {
      const int r = rt * 32 + (reg & 3) + 8 * (reg >> 2) + 4 * q32;
      float v = acc[rt][reg] + bv;
      if (ACTF == 1) v = fmaxf(v, 0.f);
      actout[r * Sout + c] = f2bf(v);
    }
}

// ---- input staging: one 32-row half-chunk (32 rows x 128 cols fp32) -------
// mmode: 0 none, 1 init maskacc, 2 accumulate
__device__ __forceinline__ void stage_half(const float* __restrict__ src, int row0,
                                           int colbase, int rowoff, short* Pb,
                                           float* maskacc, int mmode, int tid) {
  const int c4 = tid & 31, rb = tid >> 5;    // rb in [0,8)
  float4 v[4];
#pragma unroll
  for (int it = 0; it < 4; ++it)
    v[it] = *(const float4*)(src + (size_t)(row0 + rowoff + rb + it * 8) * 256 + colbase + c4 * 4);
#pragma unroll
  for (int it = 0; it < 4; ++it) {
    const int r = rowoff + rb + it * 8;
    short4 pk; pk.x = f2bf(v[it].x); pk.y = f2bf(v[it].y); pk.z = f2bf(v[it].z); pk.w = f2bf(v[it].w);
    *(short4*)(Pb + r * 136 + c4 * 4) = pk;
    if (mmode) {
      float s = v[it].x + v[it].y + v[it].z + v[it].w;
      s += __shfl_down(s, 16, 32);
      s += __shfl_down(s, 8, 32);
      s += __shfl_down(s, 4, 32);
      s += __shfl_down(s, 2, 32);
      s += __shfl_down(s, 1, 32);
      if (c4 == 0) {
        if (mmode == 1) maskacc[r] = s; else maskacc[r] += s;
      }
    }
  }
}

// Streamed first layer (N=128 out): chunks kc<splitc from src0, else src1.
template <int NCH, bool MASKA>
__device__ __forceinline__ void stream32(const float* __restrict__ src0,
                                         const float* __restrict__ src1, int splitc,
                                         const short* __restrict__ wsB,
                                         const float* __restrict__ bias,
                                         short* P, short* A, float* maskacc,
                                         int row0, int tid, int wq, int lane) {
  constexpr int KT16 = NCH * 8;
  const int n32 = lane & 31, q32 = lane >> 5;
  f32x16 acc[2];
  acc[0] = (f32x16)(0.f); acc[1] = (f32x16)(0.f);
#pragma unroll
  for (int kc = 0; kc < NCH; ++kc) {
    const bool lo = (kc < splitc);
    const float* src = lo ? src0 : src1;
    const int colbase = (lo ? kc : kc - splitc) * 128;
    const int mm = MASKA ? (kc == 0 ? 1 : (lo ? 2 : 0)) : 0;
    stage_half(src, row0, colbase, 0,  P, maskacc, mm, tid);
    stage_half(src, row0, colbase, 32, P, maskacc, mm, tid);
    __syncthreads();
    gemm32<KT16, 8>(P, 136, wsB, kc * 8, wq, acc, lane);
    __syncthreads();
  }
  epi32<1>(acc, A, 136, bias, wq * 32, n32, q32);
  __syncthreads();
}

// Layer pair: (K=128 -> N=256, ReLU) then (K=256 -> N=128, ReLU), with the
// 256-wide intermediate processed in two 128-col halves through P (acc-chain).
__device__ __forceinline__ void mid_pair(short* A, short* P,
                                         const short* __restrict__ ws1,
                                         const float* __restrict__ b1,
                                         const short* __restrict__ ws2,
                                         const float* __restrict__ b2,
                                         int wq, int lane) {
  const int n32 = lane & 31, q32 = lane >> 5;
  f32x16 acc2[2];
  acc2[0] = (f32x16)(0.f); acc2[1] = (f32x16)(0.f);
#pragma unroll
  for (int h = 0; h < 2; ++h) {
    f32x16 acc1[2];
    acc1[0] = (f32x16)(0.f); acc1[1] = (f32x16)(0.f);
    gemm32<8, 8>(A, 136, ws1, 0, h * 4 + wq, acc1, lane);   // cols h*128 + wq*32
    epi32<1>(acc1, P, 136, b1 + h * 128, wq * 32, n32, q32); // P free: synced before
    __syncthreads();
    gemm32<16, 8>(P, 136, ws2, h * 8, wq, acc2, lane);      // K rows h*128..h*128+127
    __syncthreads();
  }
  epi32<1>(acc2, A, 136, b2, wq * 32, n32, q32);            // A dead (synced above)
  __syncthreads();
}

// g3: K=128 N=256 sigmoid -> packed bf16 gate in VGPRs, two 128-col passes.
__device__ __forceinline__ void gate_layer(const short* A, const short* __restrict__ wsB,
                                           const float* __restrict__ bias,
                                           uint32_t (&gate)[2][2][8],
                                           int wq, int lane) {
  const int n32 = lane & 31;
#pragma unroll
  for (int h = 0; h < 2; ++h) {
    f32x16 acc[2];
    acc[0] = (f32x16)(0.f); acc[1] = (f32x16)(0.f);
    gemm32<8, 8>(A, 136, wsB, 0, h * 4 + wq, acc, lane);
    const float bv = bias[h * 128 + wq * 32 + n32];
#pragma unroll
    for (int rt = 0; rt < 2; ++rt)
#pragma unroll
      for (int p = 0; p < 8; ++p) {
        const float g0 = 1.f / (1.f + __expf(-(acc[rt][2 * p] + bv)));
        const float g1 = 1.f / (1.f + __expf(-(acc[rt][2 * p + 1] + bv)));
        gate[rt][h][p] = ((uint32_t)(uint16_t)f2bf(g1) << 16) | (uint32_t)(uint16_t)f2bf(g0);
      }
  }
}

// o3: K=128 N=256 in two passes, fused mask*gate*val reduce over 64 rows.
__device__ __forceinline__ void final32(const short* A, const short* __restrict__ wsB,
                                        const float* __restrict__ bias,
                                        const uint32_t (&gate)[2][2][8],
                                        const float* maskacc, float* __restrict__ out,
                                        int row0, int wq, int lane) {
  const int n32 = lane & 31, q32 = lane >> 5;
  const int b = row0 >> 8;       // 64 | 256, 4 WGs per batch
#pragma unroll
  for (int h = 0; h < 2; ++h) {
    f32x16 acc[2];
    acc[0] = (f32x16)(0.f); acc[1] = (f32x16)(0.f);
    gemm32<8, 8>(A, 136, wsB, 0, h * 4 + wq, acc, lane);
    const int c = h * 128 + wq * 32 + n32;
    const float bv = bias[c];
    float s = 0.f;
#pragma unroll
    for (int rt = 0; rt < 2; ++rt)
#pragma unroll
      for (int p = 0; p < 8; ++p) {
        const int r0 = rt * 32 + ((2 * p) & 3) + 8 * (p >> 1) + 4 * q32;  // reg=2p
        const float g0 = bf2f((short)(gate[rt][h][p] & 0xFFFF));
        const float g1 = bf2f((short)(gate[rt][h][p] >> 16));
        const float v0 = acc[rt][2 * p] + bv;
        const float v1 = acc[rt][2 * p + 1] + bv;
        if (maskacc[r0] > 0.f)     s += g0 * v0;
        if (maskacc[r0 + 1] > 0.f) s += g1 * v1;
      }
    s += __shfl_down(s, 32);
    if (lane < 32) atomicAdd(out + b * 256 + c, s);
  }
}

__global__ __launch_bounds__(NTHR, 4)
void readout_main(const float* __restrict__ h0, const float* __restrict__ hT,
                  const short* __restrict__ ws,
                  const float* __restrict__ gb0, const float* __restrict__ gb1,
                  const float* __restrict__ gb2, const float* __restrict__ gb3,
                  const float* __restrict__ ob0, const float* __restrict__ ob1,
                  const float* __restrict__ ob2, const float* __restrict__ ob3,
                  float* __restrict__ out) {
  __shared__ __align__(16) char smem[LDS_TOTAL];
  short* P  = (short*)(smem + OFF_P);      // stream buf / B2a half (disjoint lifetimes)
  short* A  = (short*)(smem + OFF_A);      // [64][136]
  float* maskacc = (float*)(smem + OFF_MASK);

  const int tid = threadIdx.x, lane = tid & 63, wq = tid >> 6;
  const int row0 = blockIdx.x * ROWS;
  uint32_t gate[2][2][8];

  // gate chain
  stream32<4, true>(h0, hT, 2, ws + 0, gb0, P, A, maskacc, row0, tid, wq, lane);
  mid_pair(A, P, ws + 65536, gb1, ws + 98304, gb2, wq, lane);
  gate_layer(A, ws + 131072, gb3, gate, wq, lane);
  // value chain (hT re-streamed, L3-warm); no sync needed after gate_layer:
  // value stream only writes P (safe) and its first barrier collects all waves.
  stream32<2, false>(hT, hT, 2, ws + 163840, ob0, P, A, maskacc, row0, tid, wq, lane);
  mid_pair(A, P, ws + 196608, ob1, ws + 229376, ob2, wq, lane);
  final32(A, ws + 262144, ob3, gate, maskacc, out, row0, wq, lane);
}

// ---- prep: weights fp32[K][N] -> bf16 fragment-ordered; zero out -----------
// ws elem off = layer_off + ((cb*(K/16) + ks)<<9) + lanei*8 + j
//   with n = cb*32 + (lanei&31), k = ks*16 + (lanei>>5)*8 + j.
__global__ void prep(const float* __restrict__ W0, const float* __restrict__ W1,
                     const float* __restrict__ W2, const float* __restrict__ W3,
                     const float* __restrict__ W4, const float* __restrict__ W5,
                     const float* __restrict__ W6, const float* __restrict__ W7,
                     short* __restrict__ ws, float* __restrict__ out) {
  const int l = blockIdx.y;
  const int le = blockIdx.x * 256 + threadIdx.x;    // < 65536
  if (l == 1) { out[le] = 0.f; out[le + 65536] = 0.f; }
  int K, N, off; const float* W;
  switch (l) {
    case 0:  K = 512; N = 128; off = 0;      W = W0; break;
    case 1:  K = 128; N = 256; off = 65536;  W = W1; break;
    case 2:  K = 256; N = 128; off = 98304;  W = W2; break;
    case 3:  K = 128; N = 256; off = 131072; W = W3; break;
    case 4:  K = 256; N = 128; off = 163840; W = W4; break;
    case 5:  K = 128; N = 256; off = 196608; W = W5; break;
    case 6:  K = 256; N = 128; off = 229376; W = W6; break;
    default: K = 128; N = 256; off = 262144; W = W7; break;
  }
  if (le >= K * N) return;
  const int j = le & 7;
  const int lanei = (le >> 3) & 63;
  const int blk = le >> 9;
  const int kt16 = K >> 4;
  const int ks = blk % kt16, cb = blk / kt16;
  const int n = cb * 32 + (lanei & 31);
  const int k = ks * 16 + (lanei >> 5) * 8 + j;
  ws[off + le] = f2bf(W[k * N + n]);    // coalesced write, gathered read
}

extern "C" void kernel_launch(void* const* d_in, const int* in_sizes, int n_in,
                              void* d_out, int out_size, void* d_ws, size_t ws_size,
                              hipStream_t stream) {
  const float* h0  = (const float*)d_in[0];
  const float* hT  = (const float*)d_in[1];
  const float* gW0 = (const float*)d_in[2];  const float* gb0 = (const float*)d_in[3];
  const float* gW1 = (const float*)d_in[4];  const float* gb1 = (const float*)d_in[5];
  const float* gW2 = (const float*)d_in[6];  const float* gb2 = (const float*)d_in[7];
  const float* gW3 = (const float*)d_in[8];  const float* gb3 = (const float*)d_in[9];
  const float* oW0 = (const float*)d_in[10]; const float* ob0 = (const float*)d_in[11];
  const float* oW1 = (const float*)d_in[12]; const float* ob1 = (const float*)d_in[13];
  const float* oW2 = (const float*)d_in[14]; const float* ob2 = (const float*)d_in[15];
  const float* oW3 = (const float*)d_in[16]; const float* ob3 = (const float*)d_in[17];
  float* out = (float*)d_out;
  short* ws  = (short*)d_ws;   // 589824 B

  prep<<<dim3(256, 8), 256, 0, stream>>>(gW0, gW1, gW2, gW3, oW0, oW1, oW2, oW3, ws, out);
  readout_main<<<NWG, NTHR, 0, stream>>>(h0, hT, ws,
                                         gb0, gb1, gb2, gb3,
                                         ob0, ob1, ob2, ob3, out);
}